// Round 11
// baseline (223.260 us; speedup 1.0000x reference)
//
#include <hip/hip_runtime.h>
#include <cstddef>
#include <cstdint>

#define D_MODEL 512
#define DK 64
#define LQ 1024
#define LK 1024
#define NB 2
#define LN_EPS 1e-6f
#define L2E2 2.8853900817779268f  // 2*log2(e)

// pack two floats to bf16x2 (RNE), low word = a
__device__ __forceinline__ uint32_t pack_bf2(float a, float b) {
  uint32_t ua = __float_as_uint(a), ub = __float_as_uint(b);
  ua = (ua + 0x7fffu + ((ua >> 16) & 1u)) >> 16;
  ub = (ub + 0x7fffu + ((ub >> 16) & 1u)) >> 16;
  return (ub << 16) | ua;
}

// ---------------- projections ----------------
// type 0: qp=q@Wq -> ab_g[row][d] = {v_d*e^{-2qp}, e^{-2qp}}
// type 1: ek=e^{2*(k@Wk)} -> ekT[batch][dp][j] u32 = bf16{ek[dp], ek[dp+32]}
// type 2: vp = v@Wv (f32 row-major)
// r9 shape: 256 thr, 16 rows/block (4 rows/wave), grid 384 — half the W
// L2 stream of the 2-rows/wave variant.
#define PR_ROWS 16
__global__ __launch_bounds__(256, 4) void proj_kernel(
    const float* __restrict__ q, const float* __restrict__ k,
    const float* __restrict__ v, const float* __restrict__ Wq,
    const float* __restrict__ Wk, const float* __restrict__ Wv,
    const float* __restrict__ v_param, float2* __restrict__ ab_g,
    uint32_t* __restrict__ ekT, float* __restrict__ vp) {
  __shared__ float rows[PR_ROWS][D_MODEL];  // 32 KB
  const int tid = threadIdx.x;
  const int type = blockIdx.x >> 7;  // 128 row-groups per type
  const int r0 = (blockIdx.x & 127) * PR_ROWS;
  const float* __restrict__ in = (type == 0) ? q : (type == 1) ? k : v;
  const float* __restrict__ W = (type == 0) ? Wq : (type == 1) ? Wk : Wv;
  {
    const float4* __restrict__ in4 = (const float4*)(in + (size_t)r0 * D_MODEL);
    float4* r4 = (float4*)&rows[0][0];
#pragma unroll
    for (int t = 0; t < 8; ++t) r4[tid + 256 * t] = in4[tid + 256 * t];
  }
  __syncthreads();
  const int lane = tid & 63;
  const int wv = tid >> 6;        // 0..3
  const int rglob = r0 + wv * 4;  // wave's first global row (mult of 4)
  const float* __restrict__ Wl = W + lane;
  float c0[4] = {0.f, 0.f, 0.f, 0.f}, c1[4] = {0.f, 0.f, 0.f, 0.f};
#pragma unroll 2
  for (int e = 0; e < D_MODEL; e += 4) {
    float w0 = Wl[(size_t)(e + 0) * DK];
    float w1 = Wl[(size_t)(e + 1) * DK];
    float w2 = Wl[(size_t)(e + 2) * DK];
    float w3 = Wl[(size_t)(e + 3) * DK];
#pragma unroll
    for (int r = 0; r < 4; ++r) {
      float4 x = *(const float4*)&rows[wv * 4 + r][e];
      c0[r] = fmaf(x.x, w0, c0[r]);
      c1[r] = fmaf(x.y, w1, c1[r]);
      c0[r] = fmaf(x.z, w2, c0[r]);
      c1[r] = fmaf(x.w, w3, c1[r]);
    }
  }
  float acc[4];
#pragma unroll
  for (int r = 0; r < 4; ++r) acc[r] = c0[r] + c1[r];
  if (type == 0) {
    float vpar = v_param[lane];
#pragma unroll
    for (int r = 0; r < 4; ++r) {
      float iv = __builtin_amdgcn_exp2f(-L2E2 * acc[r]);
      ab_g[(size_t)(rglob + r) * DK + lane] = make_float2(vpar * iv, iv);
    }
  } else if (type == 1) {
    float e4[4], h4[4];
#pragma unroll
    for (int r = 0; r < 4; ++r) {
      e4[r] = __builtin_amdgcn_exp2f(L2E2 * acc[r]);
      h4[r] = __shfl_down(e4[r], 32);  // lane d gets Ek[d+32]
    }
    if (lane < 32) {
      int b = rglob >> 10, j0 = rglob & 1023;  // rglob%4==0 -> 16B aligned
      uint4 pk;
      pk.x = pack_bf2(e4[0], h4[0]);
      pk.y = pack_bf2(e4[1], h4[1]);
      pk.z = pack_bf2(e4[2], h4[2]);
      pk.w = pack_bf2(e4[3], h4[3]);
      *(uint4*)&ekT[(size_t)b * 32 * LK + (size_t)lane * LK + j0] = pk;
    }
  } else {
#pragma unroll
    for (int r = 0; r < 4; ++r) vp[(size_t)(rglob + r) * DK + lane] = acc[r];
  }
}

// ---------------- scores + softmax -> P (attn_out) ----------------
// 256 thr (4 waves), RB=2 rows, grid 1024 (4 blocks/CU).
// NEW: explicit double-buffered software pipeline over dp-tiles of 4:
// the next tile's 16 ekT loads are issued BEFORE the current tile's ~280-
// instr compute block, so L2 latency hides under independent work (the
// r10 lesson: rolled loop exposed vmcnt latency each iteration).
#define RB 2
__global__ __launch_bounds__(256, 4) void score_kernel(
    const float2* __restrict__ ab_g, const uint32_t* __restrict__ ekT,
    float* __restrict__ attn_out) {
  __shared__ float4 ab4s[RB][32];  // 1 KB {A,B,A',B'}
  __shared__ float mred[RB][4], sred[RB][4];
  const int tid = threadIdx.x;
  const int row0 = blockIdx.x * RB;  // RB | LQ -> single batch per block
  const int batch = row0 >> 10;
  const uint32_t* __restrict__ ekT_b = ekT + (size_t)batch * 32 * LK + tid;
  if (tid < RB * 64) {
    int r = tid >> 6, d = tid & 63;
    float2 abv = ab_g[(size_t)(row0 + r) * DK + d];
    ((float2*)&ab4s[r][d & 31])[d >> 5] = abv;
  }
  __syncthreads();

  float acc[RB][4];
#pragma unroll
  for (int r = 0; r < RB; ++r)
#pragma unroll
    for (int jj = 0; jj < 4; ++jj) acc[r][jj] = 0.f;

  uint32_t bufA[4][4], bufB[4][4];  // [dd][jj], static-indexed (rule #20)

#define PREF(BUF, TP)                                                      \
  {                                                                        \
    _Pragma("unroll") for (int dd = 0; dd < 4; ++dd) {                     \
      _Pragma("unroll") for (int jj = 0; jj < 4; ++jj) {                   \
        BUF[dd][jj] = ekT_b[(size_t)((TP)*4 + dd) * LK + jj * 256];        \
      }                                                                    \
    }                                                                      \
  }

#define COMP(BUF, TP)                                                      \
  {                                                                        \
    _Pragma("unroll") for (int dd = 0; dd < 4; ++dd) {                     \
      const int dp = (TP)*4 + dd;                                          \
      float klo[4], khi[4];                                                \
      _Pragma("unroll") for (int jj = 0; jj < 4; ++jj) {                   \
        klo[jj] = __uint_as_float(BUF[dd][jj] << 16);                      \
        khi[jj] = __uint_as_float(BUF[dd][jj] & 0xffff0000u);              \
      }                                                                    \
      _Pragma("unroll") for (int r = 0; r < RB; ++r) {                     \
        float4 ab = ab4s[r][dp];                                           \
        _Pragma("unroll") for (int jj = 0; jj < 4; ++jj) {                 \
          float x1 = klo[jj] + ab.y, x2 = khi[jj] + ab.w;                  \
          float num = fmaf(ab.z, x1, ab.x * x2);                           \
          acc[r][jj] =                                                     \
              fmaf(num, __builtin_amdgcn_rcpf(x1 * x2), acc[r][jj]);       \
        }                                                                  \
      }                                                                    \
    }                                                                      \
  }

  PREF(bufA, 0);
#pragma unroll
  for (int tp = 0; tp < 8; tp += 2) {
    PREF(bufB, tp + 1);   // issue next tile's loads first
    COMP(bufA, tp);       // ~280 instrs of independent work cover latency
    if (tp + 2 < 8) PREF(bufA, tp + 2);
    COMP(bufB, tp + 1);
  }
#undef PREF
#undef COMP

  const int wave = __builtin_amdgcn_readfirstlane(tid >> 6);
  const int lane = tid & 63;

  // softmax over score = C - 2*acc -> shift by min(acc)
  {
#pragma unroll
    for (int r = 0; r < RB; ++r) {
      float pm = fminf(fminf(acc[r][0], acc[r][1]), fminf(acc[r][2], acc[r][3]));
#pragma unroll
      for (int off = 32; off > 0; off >>= 1) pm = fminf(pm, __shfl_xor(pm, off));
      if (lane == 0) mred[r][wave] = pm;
    }
    __syncthreads();
#pragma unroll
    for (int r = 0; r < RB; ++r) {
      float m = fminf(fminf(mred[r][0], mred[r][1]),
                      fminf(mred[r][2], mred[r][3]));
      float s = 0.f;
#pragma unroll
      for (int jj = 0; jj < 4; ++jj) {
        float e = __builtin_amdgcn_exp2f((m - acc[r][jj]) * L2E2);
        acc[r][jj] = e;
        s += e;
      }
#pragma unroll
      for (int off = 32; off > 0; off >>= 1) s += __shfl_xor(s, off);
      if (lane == 0) sred[r][wave] = s;
    }
    __syncthreads();
#pragma unroll
    for (int r = 0; r < RB; ++r) {
      float inv = __builtin_amdgcn_rcpf(sred[r][0] + sred[r][1] + sred[r][2] +
                                        sred[r][3]);
      float* __restrict__ arow = attn_out + (size_t)(row0 + r) * LK;
#pragma unroll
      for (int jj = 0; jj < 4; ++jj)
        arow[tid + jj * 256] = acc[r][jj] * inv;
    }
  }
}

// ---------------- PV + FC + LN ----------------
// 512 thr (8 waves), RB=4 rows, grid 512 -> 16 waves/CU. P staged from
// attn_out (L2-warm).
#define PRB 4
__global__ __launch_bounds__(512, 4) void pvfc_kernel(
    const float* __restrict__ attn, const float* __restrict__ vp,
    const float* __restrict__ resid, const float* __restrict__ Wfc,
    const float* __restrict__ gamma, const float* __restrict__ beta,
    float* __restrict__ out) {
  __shared__ float sc[PRB][LK];                  // 16 KB P rows
  __shared__ float4 pvred[8][PRB][16];           // 8 KB PV partials
  __shared__ __align__(16) float ovlT[DK][PRB];  // 1 KB, e-major
  __shared__ float red[2][PRB][8];               // LN reductions
  const int tid = threadIdx.x;
  const int row0 = blockIdx.x * PRB;
  const int batch = row0 >> 10;
  const float* __restrict__ vp_b = vp + (size_t)batch * LK * DK;
  {
    const float4* __restrict__ a4 = (const float4*)(attn + (size_t)row0 * LK);
    float4* s4 = (float4*)&sc[0][0];
#pragma unroll
    for (int t = 0; t < 2; ++t) s4[tid + 512 * t] = a4[tid + 512 * t];
  }
  __syncthreads();

  const int wave = __builtin_amdgcn_readfirstlane(tid >> 6);
  const int lane = tid & 63;

  // PV: wave owns 128-j slice; vp read once per block per j (serves 4 rows)
  {
    const int jj = lane >> 4, l16 = lane & 15;
    const float4* __restrict__ vp4 = (const float4*)vp_b;
    float4 a[PRB];
#pragma unroll
    for (int r = 0; r < PRB; ++r) a[r] = make_float4(0.f, 0.f, 0.f, 0.f);
#pragma unroll 4
    for (int it = 0; it < 32; ++it) {
      int j = (wave << 7) + (it << 2) + jj;
      float4 vv = vp4[(size_t)j * (DK / 4) + l16];
#pragma unroll
      for (int r = 0; r < PRB; ++r) {
        float pw = sc[r][j];
        a[r].x = fmaf(pw, vv.x, a[r].x);
        a[r].y = fmaf(pw, vv.y, a[r].y);
        a[r].z = fmaf(pw, vv.z, a[r].z);
        a[r].w = fmaf(pw, vv.w, a[r].w);
      }
    }
#pragma unroll
    for (int r = 0; r < PRB; ++r) {
      a[r].x += __shfl_xor(a[r].x, 16); a[r].y += __shfl_xor(a[r].y, 16);
      a[r].z += __shfl_xor(a[r].z, 16); a[r].w += __shfl_xor(a[r].w, 16);
      a[r].x += __shfl_xor(a[r].x, 32); a[r].y += __shfl_xor(a[r].y, 32);
      a[r].z += __shfl_xor(a[r].z, 32); a[r].w += __shfl_xor(a[r].w, 32);
    }
    if (jj == 0) {
#pragma unroll
      for (int r = 0; r < PRB; ++r) pvred[wave][r][l16] = a[r];
    }
  }
  __syncthreads();
  if (tid < 64) {  // final PV reduce -> transposed ovlT[e][r]
    int r = tid >> 4, l16 = tid & 15;
    float4 s = make_float4(0.f, 0.f, 0.f, 0.f);
#pragma unroll
    for (int w = 0; w < 8; ++w) {
      float4 t = pvred[w][r][l16];
      s.x += t.x; s.y += t.y; s.z += t.z; s.w += t.w;
    }
    ovlT[l16 * 4 + 0][r] = s.x;
    ovlT[l16 * 4 + 1][r] = s.y;
    ovlT[l16 * 4 + 2][r] = s.z;
    ovlT[l16 * 4 + 3][r] = s.w;
  }
  __syncthreads();

  // FC + residual + LN: thread owns column c = tid for 4 rows
  {
    const int c = tid;
    float y[PRB];
#pragma unroll
    for (int r = 0; r < PRB; ++r)
      y[r] = resid[(size_t)(row0 + r) * D_MODEL + c];
#pragma unroll 4
    for (int e = 0; e < DK; ++e) {
      float w = Wfc[(size_t)e * D_MODEL + c];
      float4 ov = *(const float4*)&ovlT[e][0];
      y[0] = fmaf(ov.x, w, y[0]);
      y[1] = fmaf(ov.y, w, y[1]);
      y[2] = fmaf(ov.z, w, y[2]);
      y[3] = fmaf(ov.w, w, y[3]);
    }
#pragma unroll
    for (int r = 0; r < PRB; ++r) {
      float s = y[r];
#pragma unroll
      for (int off = 32; off > 0; off >>= 1) s += __shfl_xor(s, off);
      if (lane == 0) red[0][r][wave] = s;
    }
    __syncthreads();
    float mu[PRB];
#pragma unroll
    for (int r = 0; r < PRB; ++r) {
      float s = 0.f;
#pragma unroll
      for (int w = 0; w < 8; ++w) s += red[0][r][w];
      mu[r] = s * (1.0f / D_MODEL);
    }
#pragma unroll
    for (int r = 0; r < PRB; ++r) {
      float d = y[r] - mu[r];
      float s = d * d;
#pragma unroll
      for (int off = 32; off > 0; off >>= 1) s += __shfl_xor(s, off);
      if (lane == 0) red[1][r][wave] = s;
    }
    __syncthreads();
    float gg = gamma[c], bb = beta[c];
#pragma unroll
    for (int r = 0; r < PRB; ++r) {
      float s = 0.f;
#pragma unroll
      for (int w = 0; w < 8; ++w) s += red[1][r][w];
      float var = s * (1.0f / D_MODEL);
      float rstd = rsqrtf(var + LN_EPS);
      out[(size_t)(row0 + r) * D_MODEL + c] = (y[r] - mu[r]) * rstd * gg + bb;
    }
  }
}

extern "C" void kernel_launch(void* const* d_in, const int* in_sizes, int n_in,
                              void* d_out, int out_size, void* d_ws,
                              size_t ws_size, hipStream_t stream) {
  const float* q = (const float*)d_in[0];
  const float* k = (const float*)d_in[1];
  const float* v = (const float*)d_in[2];
  const float* Wq = (const float*)d_in[3];
  const float* Wk = (const float*)d_in[4];
  const float* Wv = (const float*)d_in[5];
  const float* v_param = (const float*)d_in[6];
  const float* Wfc = (const float*)d_in[7];
  const float* gamma = (const float*)d_in[8];
  const float* beta = (const float*)d_in[9];

  float* out = (float*)d_out;                     // [B*LQ*D_MODEL]
  float* attn = out + (size_t)NB * LQ * D_MODEL;  // [B*LQ*LK]

  float* base = (float*)d_ws;
  float2* ab_g = (float2*)base;                                  // [2048*64]
  uint32_t* ekT = (uint32_t*)(base + (size_t)2 * NB * LQ * DK);  // [2*32*1024]
  float* vp = base + (size_t)2 * NB * LQ * DK + NB * 32 * LK;    // [2048*64]

  hipLaunchKernelGGL(proj_kernel, dim3(3 * 128), dim3(256), 0, stream, q, k, v,
                     Wq, Wk, Wv, v_param, ab_g, ekT, vp);
  hipLaunchKernelGGL(score_kernel, dim3(NB * LQ / RB), dim3(256), 0, stream,
                     ab_g, ekT, attn);
  hipLaunchKernelGGL(pvfc_kernel, dim3(NB * LQ / PRB), dim3(512), 0, stream,
                     attn, vp, q, Wfc, gamma, beta, out);
}

// Round 12
// 66.305 us; speedup vs baseline: 3.3671x; 3.3671x over previous
//
#include <hip/hip_runtime.h>
#include <cstddef>
#include <cstdint>

#define D_MODEL 512
#define DK 64
#define LQ 1024
#define LK 1024
#define NB 2
#define LN_EPS 1e-6f
#define L2E2 2.8853900817779268f  // 2*log2(e)

// pack two floats to bf16x2 (RNE), low word = a
__device__ __forceinline__ uint32_t pack_bf2(float a, float b) {
  uint32_t ua = __float_as_uint(a), ub = __float_as_uint(b);
  ua = (ua + 0x7fffu + ((ua >> 16) & 1u)) >> 16;
  ub = (ub + 0x7fffu + ((ub >> 16) & 1u)) >> 16;
  return (ub << 16) | ua;
}

// ---------------- projections ----------------
// type 0: qp=q@Wq -> ab4[row][dp] = float4{A_dp, B_dp, A_dp+32, B_dp+32}
//         with A = v_d*e^{-2qp}, B = e^{-2qp}  (block-uniform score operands)
// type 1: ek=e^{2*(k@Wk)} -> ekT[batch][dp][j] u32 = bf16{ek[dp], ek[dp+32]}
// type 2: vp = v@Wv (f32 row-major)
// 256 thr (4 waves), 16 rows/block (4/wave), grid 384; e-loop unroll 4.
#define PR_ROWS 16
__global__ __launch_bounds__(256, 4) void proj_kernel(
    const float* __restrict__ q, const float* __restrict__ k,
    const float* __restrict__ v, const float* __restrict__ Wq,
    const float* __restrict__ Wk, const float* __restrict__ Wv,
    const float* __restrict__ v_param, float4* __restrict__ ab4,
    uint32_t* __restrict__ ekT, float* __restrict__ vp) {
  __shared__ float rows[PR_ROWS][D_MODEL];  // 32 KB
  const int tid = threadIdx.x;
  const int type = blockIdx.x >> 7;  // 128 row-groups per type
  const int r0 = (blockIdx.x & 127) * PR_ROWS;
  const float* __restrict__ in = (type == 0) ? q : (type == 1) ? k : v;
  const float* __restrict__ W = (type == 0) ? Wq : (type == 1) ? Wk : Wv;
  {
    const float4* __restrict__ in4 = (const float4*)(in + (size_t)r0 * D_MODEL);
    float4* r4 = (float4*)&rows[0][0];
#pragma unroll
    for (int t = 0; t < 8; ++t) r4[tid + 256 * t] = in4[tid + 256 * t];
  }
  __syncthreads();
  const int lane = tid & 63;
  const int wv = tid >> 6;        // 0..3
  const int rglob = r0 + wv * 4;  // wave's first global row (mult of 4)
  const float* __restrict__ Wl = W + lane;
  float c0[4] = {0.f, 0.f, 0.f, 0.f}, c1[4] = {0.f, 0.f, 0.f, 0.f};
#pragma unroll 4
  for (int e = 0; e < D_MODEL; e += 4) {
    float w0 = Wl[(size_t)(e + 0) * DK];
    float w1 = Wl[(size_t)(e + 1) * DK];
    float w2 = Wl[(size_t)(e + 2) * DK];
    float w3 = Wl[(size_t)(e + 3) * DK];
#pragma unroll
    for (int r = 0; r < 4; ++r) {
      float4 x = *(const float4*)&rows[wv * 4 + r][e];
      c0[r] = fmaf(x.x, w0, c0[r]);
      c1[r] = fmaf(x.y, w1, c1[r]);
      c0[r] = fmaf(x.z, w2, c0[r]);
      c1[r] = fmaf(x.w, w3, c1[r]);
    }
  }
  float acc[4];
#pragma unroll
  for (int r = 0; r < 4; ++r) acc[r] = c0[r] + c1[r];
  if (type == 0) {
    float vpar = v_param[lane];
#pragma unroll
    for (int r = 0; r < 4; ++r) {
      float iv = __builtin_amdgcn_exp2f(-L2E2 * acc[r]);
      float A = vpar * iv, B = iv;
      float Ah = __shfl_down(A, 32);  // lane d gets A_{d+32}
      float Bh = __shfl_down(B, 32);
      if (lane < 32)
        ab4[(size_t)(rglob + r) * 32 + lane] = make_float4(A, B, Ah, Bh);
    }
  } else if (type == 1) {
    float e4[4], h4[4];
#pragma unroll
    for (int r = 0; r < 4; ++r) {
      e4[r] = __builtin_amdgcn_exp2f(L2E2 * acc[r]);
      h4[r] = __shfl_down(e4[r], 32);  // lane d gets Ek[d+32]
    }
    if (lane < 32) {
      int b = rglob >> 10, j0 = rglob & 1023;  // rglob%4==0 -> 16B aligned
      uint4 pk;
      pk.x = pack_bf2(e4[0], h4[0]);
      pk.y = pack_bf2(e4[1], h4[1]);
      pk.z = pack_bf2(e4[2], h4[2]);
      pk.w = pack_bf2(e4[3], h4[3]);
      *(uint4*)&ekT[(size_t)b * 32 * LK + (size_t)lane * LK + j0] = pk;
    }
  } else {
#pragma unroll
    for (int r = 0; r < 4; ++r) vp[(size_t)(rglob + r) * DK + lane] = acc[r];
  }
}

// ---------------- scores + softmax -> P (attn_out) ----------------
// 256 thr (4 waves), RB=2 rows, grid 1024 (4 blocks/CU).
// ZERO LDS in the main loop: A/B read via wave-UNIFORM global loads
// (compiler scalarizes to s_load / L1 broadcast; SGPR src is free in VALU).
// Quad-rcp: one reciprocal per FOUR d-terms (overflow-safe, den <= ~e^40).
#define RB 2
__global__ __launch_bounds__(256, 4) void score_kernel(
    const float4* __restrict__ ab4, const uint32_t* __restrict__ ekT,
    float* __restrict__ attn_out) {
  __shared__ float mred[RB][4], sred[RB][4];
  const int tid = threadIdx.x;
  const int row0 = blockIdx.x * RB;  // RB | LQ -> single batch per block
  const int batch = row0 >> 10;
  const uint32_t* __restrict__ ekT_b = ekT + (size_t)batch * 32 * LK + tid;
  const float4* __restrict__ abr0 = ab4 + (size_t)(row0 + 0) * 32;
  const float4* __restrict__ abr1 = ab4 + (size_t)(row0 + 1) * 32;

  float acc0[4] = {0.f, 0.f, 0.f, 0.f};  // [jj], static-indexed only
  float acc1[4] = {0.f, 0.f, 0.f, 0.f};

#pragma unroll
  for (int qd = 0; qd < 16; ++qd) {  // quad covers dp = 2qd, 2qd+1
    uint32_t k0[4], k1[4];
#pragma unroll
    for (int jj = 0; jj < 4; ++jj) {
      k0[jj] = ekT_b[(size_t)(2 * qd + 0) * LK + jj * 256];
      k1[jj] = ekT_b[(size_t)(2 * qd + 1) * LK + jj * 256];
    }
    // wave-uniform A/B loads (no tid in address)
    float4 p0 = abr0[2 * qd + 0], q0 = abr0[2 * qd + 1];
    float4 p1 = abr1[2 * qd + 0], q1 = abr1[2 * qd + 1];
#pragma unroll
    for (int jj = 0; jj < 4; ++jj) {
      float klo0 = __uint_as_float(k0[jj] << 16);
      float khi0 = __uint_as_float(k0[jj] & 0xffff0000u);
      float klo1 = __uint_as_float(k1[jj] << 16);
      float khi1 = __uint_as_float(k1[jj] & 0xffff0000u);
      {  // row 0: A1/x1+A2/x2+A3/x3+A4/x4 via single rcp
        float x1 = klo0 + p0.y, x2 = khi0 + p0.w;
        float x3 = klo1 + q0.y, x4 = khi1 + q0.w;
        float p12 = x1 * x2, p34 = x3 * x4;
        float n12 = fmaf(p0.z, x1, p0.x * x2);
        float n34 = fmaf(q0.z, x3, q0.x * x4);
        float num = fmaf(n34, p12, n12 * p34);
        acc0[jj] = fmaf(num, __builtin_amdgcn_rcpf(p12 * p34), acc0[jj]);
      }
      {  // row 1
        float x1 = klo0 + p1.y, x2 = khi0 + p1.w;
        float x3 = klo1 + q1.y, x4 = khi1 + q1.w;
        float p12 = x1 * x2, p34 = x3 * x4;
        float n12 = fmaf(p1.z, x1, p1.x * x2);
        float n34 = fmaf(q1.z, x3, q1.x * x4);
        float num = fmaf(n34, p12, n12 * p34);
        acc1[jj] = fmaf(num, __builtin_amdgcn_rcpf(p12 * p34), acc1[jj]);
      }
    }
  }

  const int wave = __builtin_amdgcn_readfirstlane(tid >> 6);
  const int lane = tid & 63;

  // softmax over score = C - 2*acc -> shift by min(acc)
  {
    float pm0 = fminf(fminf(acc0[0], acc0[1]), fminf(acc0[2], acc0[3]));
    float pm1 = fminf(fminf(acc1[0], acc1[1]), fminf(acc1[2], acc1[3]));
#pragma unroll
    for (int off = 32; off > 0; off >>= 1) {
      pm0 = fminf(pm0, __shfl_xor(pm0, off));
      pm1 = fminf(pm1, __shfl_xor(pm1, off));
    }
    if (lane == 0) {
      mred[0][wave] = pm0;
      mred[1][wave] = pm1;
    }
    __syncthreads();
    float m0 = fminf(fminf(mred[0][0], mred[0][1]), fminf(mred[0][2], mred[0][3]));
    float m1 = fminf(fminf(mred[1][0], mred[1][1]), fminf(mred[1][2], mred[1][3]));
    float s0 = 0.f, s1 = 0.f;
#pragma unroll
    for (int jj = 0; jj < 4; ++jj) {
      float e0 = __builtin_amdgcn_exp2f((m0 - acc0[jj]) * L2E2);
      float e1 = __builtin_amdgcn_exp2f((m1 - acc1[jj]) * L2E2);
      acc0[jj] = e0; s0 += e0;
      acc1[jj] = e1; s1 += e1;
    }
#pragma unroll
    for (int off = 32; off > 0; off >>= 1) {
      s0 += __shfl_xor(s0, off);
      s1 += __shfl_xor(s1, off);
    }
    if (lane == 0) {
      sred[0][wave] = s0;
      sred[1][wave] = s1;
    }
    __syncthreads();
    float inv0 = __builtin_amdgcn_rcpf(sred[0][0] + sred[0][1] + sred[0][2] +
                                       sred[0][3]);
    float inv1 = __builtin_amdgcn_rcpf(sred[1][0] + sred[1][1] + sred[1][2] +
                                       sred[1][3]);
    float* __restrict__ ar0 = attn_out + (size_t)(row0 + 0) * LK;
    float* __restrict__ ar1 = attn_out + (size_t)(row0 + 1) * LK;
#pragma unroll
    for (int jj = 0; jj < 4; ++jj) {
      ar0[tid + jj * 256] = acc0[jj] * inv0;
      ar1[tid + jj * 256] = acc1[jj] * inv1;
    }
  }
}

// ---------------- PV + FC + LN ----------------
// 512 thr (8 waves), PRB=4 rows, grid 512. P staged from attn_out (L2-warm).
#define PRB 4
__global__ __launch_bounds__(512, 4) void pvfc_kernel(
    const float* __restrict__ attn, const float* __restrict__ vp,
    const float* __restrict__ resid, const float* __restrict__ Wfc,
    const float* __restrict__ gamma, const float* __restrict__ beta,
    float* __restrict__ out) {
  __shared__ float sc[PRB][LK];                  // 16 KB P rows
  __shared__ float4 pvred[8][PRB][16];           // 8 KB PV partials
  __shared__ __align__(16) float ovlT[DK][PRB];  // 1 KB, e-major
  __shared__ float red[2][PRB][8];               // LN reductions
  const int tid = threadIdx.x;
  const int row0 = blockIdx.x * PRB;
  const int batch = row0 >> 10;
  const float* __restrict__ vp_b = vp + (size_t)batch * LK * DK;
  {
    const float4* __restrict__ a4 = (const float4*)(attn + (size_t)row0 * LK);
    float4* s4 = (float4*)&sc[0][0];
#pragma unroll
    for (int t = 0; t < 2; ++t) s4[tid + 512 * t] = a4[tid + 512 * t];
  }
  __syncthreads();

  const int wave = __builtin_amdgcn_readfirstlane(tid >> 6);
  const int lane = tid & 63;

  // PV: wave owns 128-j slice; vp read once per block per j (serves 4 rows)
  {
    const int jj = lane >> 4, l16 = lane & 15;
    const float4* __restrict__ vp4 = (const float4*)vp_b;
    float4 a[PRB];
#pragma unroll
    for (int r = 0; r < PRB; ++r) a[r] = make_float4(0.f, 0.f, 0.f, 0.f);
#pragma unroll 4
    for (int it = 0; it < 32; ++it) {
      int j = (wave << 7) + (it << 2) + jj;
      float4 vv = vp4[(size_t)j * (DK / 4) + l16];
#pragma unroll
      for (int r = 0; r < PRB; ++r) {
        float pw = sc[r][j];
        a[r].x = fmaf(pw, vv.x, a[r].x);
        a[r].y = fmaf(pw, vv.y, a[r].y);
        a[r].z = fmaf(pw, vv.z, a[r].z);
        a[r].w = fmaf(pw, vv.w, a[r].w);
      }
    }
#pragma unroll
    for (int r = 0; r < PRB; ++r) {
      a[r].x += __shfl_xor(a[r].x, 16); a[r].y += __shfl_xor(a[r].y, 16);
      a[r].z += __shfl_xor(a[r].z, 16); a[r].w += __shfl_xor(a[r].w, 16);
      a[r].x += __shfl_xor(a[r].x, 32); a[r].y += __shfl_xor(a[r].y, 32);
      a[r].z += __shfl_xor(a[r].z, 32); a[r].w += __shfl_xor(a[r].w, 32);
    }
    if (jj == 0) {
#pragma unroll
      for (int r = 0; r < PRB; ++r) pvred[wave][r][l16] = a[r];
    }
  }
  __syncthreads();
  if (tid < 64) {  // final PV reduce -> transposed ovlT[e][r]
    int r = tid >> 4, l16 = tid & 15;
    float4 s = make_float4(0.f, 0.f, 0.f, 0.f);
#pragma unroll
    for (int w = 0; w < 8; ++w) {
      float4 t = pvred[w][r][l16];
      s.x += t.x; s.y += t.y; s.z += t.z; s.w += t.w;
    }
    ovlT[l16 * 4 + 0][r] = s.x;
    ovlT[l16 * 4 + 1][r] = s.y;
    ovlT[l16 * 4 + 2][r] = s.z;
    ovlT[l16 * 4 + 3][r] = s.w;
  }
  __syncthreads();

  // FC + residual + LN: thread owns column c = tid for 4 rows
  {
    const int c = tid;
    float y[PRB];
#pragma unroll
    for (int r = 0; r < PRB; ++r)
      y[r] = resid[(size_t)(row0 + r) * D_MODEL + c];
#pragma unroll 4
    for (int e = 0; e < DK; ++e) {
      float w = Wfc[(size_t)e * D_MODEL + c];
      float4 ov = *(const float4*)&ovlT[e][0];
      y[0] = fmaf(ov.x, w, y[0]);
      y[1] = fmaf(ov.y, w, y[1]);
      y[2] = fmaf(ov.z, w, y[2]);
      y[3] = fmaf(ov.w, w, y[3]);
    }
#pragma unroll
    for (int r = 0; r < PRB; ++r) {
      float s = y[r];
#pragma unroll
      for (int off = 32; off > 0; off >>= 1) s += __shfl_xor(s, off);
      if (lane == 0) red[0][r][wave] = s;
    }
    __syncthreads();
    float mu[PRB];
#pragma unroll
    for (int r = 0; r < PRB; ++r) {
      float s = 0.f;
#pragma unroll
      for (int w = 0; w < 8; ++w) s += red[0][r][w];
      mu[r] = s * (1.0f / D_MODEL);
    }
#pragma unroll
    for (int r = 0; r < PRB; ++r) {
      float d = y[r] - mu[r];
      float s = d * d;
#pragma unroll
      for (int off = 32; off > 0; off >>= 1) s += __shfl_xor(s, off);
      if (lane == 0) red[1][r][wave] = s;
    }
    __syncthreads();
    float gg = gamma[c], bb = beta[c];
#pragma unroll
    for (int r = 0; r < PRB; ++r) {
      float s = 0.f;
#pragma unroll
      for (int w = 0; w < 8; ++w) s += red[1][r][w];
      float var = s * (1.0f / D_MODEL);
      float rstd = rsqrtf(var + LN_EPS);
      out[(size_t)(row0 + r) * D_MODEL + c] = (y[r] - mu[r]) * rstd * gg + bb;
    }
  }
}

extern "C" void kernel_launch(void* const* d_in, const int* in_sizes, int n_in,
                              void* d_out, int out_size, void* d_ws,
                              size_t ws_size, hipStream_t stream) {
  const float* q = (const float*)d_in[0];
  const float* k = (const float*)d_in[1];
  const float* v = (const float*)d_in[2];
  const float* Wq = (const float*)d_in[3];
  const float* Wk = (const float*)d_in[4];
  const float* Wv = (const float*)d_in[5];
  const float* v_param = (const float*)d_in[6];
  const float* Wfc = (const float*)d_in[7];
  const float* gamma = (const float*)d_in[8];
  const float* beta = (const float*)d_in[9];

  float* out = (float*)d_out;                     // [B*LQ*D_MODEL]
  float* attn = out + (size_t)NB * LQ * D_MODEL;  // [B*LQ*LK]

  float* base = (float*)d_ws;
  float4* ab4 = (float4*)base;                                   // [2048*32] f4
  uint32_t* ekT = (uint32_t*)(base + (size_t)4 * NB * LQ * 32);  // [2*32*1024]
  float* vp = base + (size_t)4 * NB * LQ * 32 + NB * 32 * LK;    // [2048*64]

  hipLaunchKernelGGL(proj_kernel, dim3(3 * 128), dim3(256), 0, stream, q, k, v,
                     Wq, Wk, Wv, v_param, ab4, ekT, vp);
  hipLaunchKernelGGL(score_kernel, dim3(NB * LQ / RB), dim3(256), 0, stream,
                     ab4, ekT, attn);
  hipLaunchKernelGGL(pvfc_kernel, dim3(NB * LQ / PRB), dim3(512), 0, stream,
                     attn, vp, q, Wfc, gamma, beta, out);
}

// Round 13
// 53.921 us; speedup vs baseline: 4.1405x; 1.2297x over previous
//
#include <hip/hip_runtime.h>
#include <cstddef>
#include <cstdint>

#define D_MODEL 512
#define DK 64
#define LQ 1024
#define LK 1024
#define NB 2
#define LN_EPS 1e-6f
#define L2E2 2.8853900817779268f  // 2*log2(e)

// ---------------- projections ----------------
// type 0: qp=q@Wq -> ab4[row][dp] = float4{A_dp, B_dp, A_dp+32, B_dp+32}
//         with A = v_d*e^{-2qp}, B = e^{-2qp}
// type 1: ek=e^{2*(k@Wk)} -> ekT2[batch][dp][j] = float2{ek[dp], ek[dp+32]}
//         (f32 now: same load count in score, no unpack, no bf16 error)
// type 2: vp = v@Wv (f32 row-major)
// 256 thr (4 waves), 16 rows/block (4/wave), grid 384.
#define PR_ROWS 16
__global__ __launch_bounds__(256, 4) void proj_kernel(
    const float* __restrict__ q, const float* __restrict__ k,
    const float* __restrict__ v, const float* __restrict__ Wq,
    const float* __restrict__ Wk, const float* __restrict__ Wv,
    const float* __restrict__ v_param, float4* __restrict__ ab4,
    float2* __restrict__ ekT2, float* __restrict__ vp) {
  __shared__ float rows[PR_ROWS][D_MODEL];  // 32 KB
  const int tid = threadIdx.x;
  const int type = blockIdx.x >> 7;  // 128 row-groups per type
  const int r0 = (blockIdx.x & 127) * PR_ROWS;
  const float* __restrict__ in = (type == 0) ? q : (type == 1) ? k : v;
  const float* __restrict__ W = (type == 0) ? Wq : (type == 1) ? Wk : Wv;
  {
    const float4* __restrict__ in4 = (const float4*)(in + (size_t)r0 * D_MODEL);
    float4* r4 = (float4*)&rows[0][0];
#pragma unroll
    for (int t = 0; t < 8; ++t) r4[tid + 256 * t] = in4[tid + 256 * t];
  }
  __syncthreads();
  const int lane = tid & 63;
  const int wv = tid >> 6;        // 0..3
  const int rglob = r0 + wv * 4;  // wave's first global row (mult of 4)
  const float* __restrict__ Wl = W + lane;
  float c0[4] = {0.f, 0.f, 0.f, 0.f}, c1[4] = {0.f, 0.f, 0.f, 0.f};
#pragma unroll 4
  for (int e = 0; e < D_MODEL; e += 4) {
    float w0 = Wl[(size_t)(e + 0) * DK];
    float w1 = Wl[(size_t)(e + 1) * DK];
    float w2 = Wl[(size_t)(e + 2) * DK];
    float w3 = Wl[(size_t)(e + 3) * DK];
#pragma unroll
    for (int r = 0; r < 4; ++r) {
      float4 x = *(const float4*)&rows[wv * 4 + r][e];
      c0[r] = fmaf(x.x, w0, c0[r]);
      c1[r] = fmaf(x.y, w1, c1[r]);
      c0[r] = fmaf(x.z, w2, c0[r]);
      c1[r] = fmaf(x.w, w3, c1[r]);
    }
  }
  float acc[4];
#pragma unroll
  for (int r = 0; r < 4; ++r) acc[r] = c0[r] + c1[r];
  if (type == 0) {
    float vpar = v_param[lane];
#pragma unroll
    for (int r = 0; r < 4; ++r) {
      float iv = __builtin_amdgcn_exp2f(-L2E2 * acc[r]);
      float A = vpar * iv, B = iv;
      float Ah = __shfl_down(A, 32);  // lane d gets A_{d+32}
      float Bh = __shfl_down(B, 32);
      if (lane < 32)
        ab4[(size_t)(rglob + r) * 32 + lane] = make_float4(A, B, Ah, Bh);
    }
  } else if (type == 1) {
    float e4[4], h4[4];
#pragma unroll
    for (int r = 0; r < 4; ++r) {
      e4[r] = __builtin_amdgcn_exp2f(L2E2 * acc[r]);
      h4[r] = __shfl_down(e4[r], 32);  // lane d gets Ek[d+32]
    }
    if (lane < 32) {
      int b = rglob >> 10, j0 = rglob & 1023;  // rglob%4==0 -> 16B aligned
      float2* bp = ekT2 + (size_t)b * 32 * LK + (size_t)lane * LK + j0;
      *(float4*)bp = make_float4(e4[0], h4[0], e4[1], h4[1]);
      *(float4*)(bp + 2) = make_float4(e4[2], h4[2], e4[3], h4[3]);
    }
  } else {
#pragma unroll
    for (int r = 0; r < 4; ++r) vp[(size_t)(rglob + r) * DK + lane] = acc[r];
  }
}

// ---------------- fused scores + softmax + PV + FC + LN ----------------
// 256 thr (4 waves), RB=4 rows/block, grid 512. Score loop: zero LDS,
// wave-uniform A/B loads (s_load), quad-rcp, f32 K (no unpack). P goes
// register -> attn_out (write-once) + LDS sc[] -> PV. One kernel: no
// launch gap, no global P re-read (the r12 lesson: phase/launch overhead
// and the P round-trip were the plateau, not the score math).
#define RB 4
__global__ __launch_bounds__(256, 4) void attn_kernel(
    const float4* __restrict__ ab4, const float2* __restrict__ ekT2,
    const float* __restrict__ vp, const float* __restrict__ resid,
    const float* __restrict__ Wfc, const float* __restrict__ gamma,
    const float* __restrict__ beta, float* __restrict__ out,
    float* __restrict__ attn_out) {
  __shared__ float sc[RB][LK];                  // 16 KB P rows
  __shared__ float4 pvred[4][RB][16];           // 4 KB PV partials
  __shared__ __align__(16) float ovlT[DK][RB];  // 1 KB, e-major
  __shared__ float red[2][RB][4];               // LN reductions
  __shared__ float mred[RB][4], sred[RB][4];
  const int tid = threadIdx.x;
  const int row0 = blockIdx.x * RB;  // RB | LQ -> single batch per block
  const int batch = row0 >> 10;
  const float2* __restrict__ ekT_b = ekT2 + (size_t)batch * 32 * LK + tid;
  const float* __restrict__ vp_b = vp + (size_t)batch * LK * DK;
  const float4* __restrict__ abr0 = ab4 + (size_t)(row0 + 0) * 32;
  const float4* __restrict__ abr1 = ab4 + (size_t)(row0 + 1) * 32;
  const float4* __restrict__ abr2 = ab4 + (size_t)(row0 + 2) * 32;
  const float4* __restrict__ abr3 = ab4 + (size_t)(row0 + 3) * 32;

  float a0[4] = {0.f, 0.f, 0.f, 0.f};  // [jj] row 0, static-indexed
  float a1[4] = {0.f, 0.f, 0.f, 0.f};
  float a2[4] = {0.f, 0.f, 0.f, 0.f};
  float a3[4] = {0.f, 0.f, 0.f, 0.f};

#pragma unroll
  for (int qd = 0; qd < 16; ++qd) {  // quad covers dp = 2qd, 2qd+1
    float2 k0[4], k1[4];
#pragma unroll
    for (int jj = 0; jj < 4; ++jj) {
      k0[jj] = ekT_b[(size_t)(2 * qd + 0) * LK + jj * 256];
      k1[jj] = ekT_b[(size_t)(2 * qd + 1) * LK + jj * 256];
    }
    // wave-uniform A/B loads (no tid in address -> scalarized)
    float4 P0 = abr0[2 * qd], Q0 = abr0[2 * qd + 1];
    float4 P1 = abr1[2 * qd], Q1 = abr1[2 * qd + 1];
    float4 P2 = abr2[2 * qd], Q2 = abr2[2 * qd + 1];
    float4 P3 = abr3[2 * qd], Q3 = abr3[2 * qd + 1];
#pragma unroll
    for (int jj = 0; jj < 4; ++jj) {
#define QUAD(PP, QQ, ACC)                                                  \
  {                                                                        \
    float x1 = k0[jj].x + PP.y, x2 = k0[jj].y + PP.w;                      \
    float x3 = k1[jj].x + QQ.y, x4 = k1[jj].y + QQ.w;                      \
    float p12 = x1 * x2, p34 = x3 * x4;                                    \
    float n12 = fmaf(PP.z, x1, PP.x * x2);                                 \
    float n34 = fmaf(QQ.z, x3, QQ.x * x4);                                 \
    float num = fmaf(n34, p12, n12 * p34);                                 \
    ACC[jj] = fmaf(num, __builtin_amdgcn_rcpf(p12 * p34), ACC[jj]);        \
  }
      QUAD(P0, Q0, a0)
      QUAD(P1, Q1, a1)
      QUAD(P2, Q2, a2)
      QUAD(P3, Q3, a3)
#undef QUAD
    }
  }

  const int wave = __builtin_amdgcn_readfirstlane(tid >> 6);
  const int lane = tid & 63;

  // softmax over score = C - 2*acc -> shift by min(acc); all waves, 4 rows
  {
    float pm0 = fminf(fminf(a0[0], a0[1]), fminf(a0[2], a0[3]));
    float pm1 = fminf(fminf(a1[0], a1[1]), fminf(a1[2], a1[3]));
    float pm2 = fminf(fminf(a2[0], a2[1]), fminf(a2[2], a2[3]));
    float pm3 = fminf(fminf(a3[0], a3[1]), fminf(a3[2], a3[3]));
#pragma unroll
    for (int off = 32; off > 0; off >>= 1) {
      pm0 = fminf(pm0, __shfl_xor(pm0, off));
      pm1 = fminf(pm1, __shfl_xor(pm1, off));
      pm2 = fminf(pm2, __shfl_xor(pm2, off));
      pm3 = fminf(pm3, __shfl_xor(pm3, off));
    }
    if (lane == 0) {
      mred[0][wave] = pm0; mred[1][wave] = pm1;
      mred[2][wave] = pm2; mred[3][wave] = pm3;
    }
    __syncthreads();
    float m0 = fminf(fminf(mred[0][0], mred[0][1]), fminf(mred[0][2], mred[0][3]));
    float m1 = fminf(fminf(mred[1][0], mred[1][1]), fminf(mred[1][2], mred[1][3]));
    float m2 = fminf(fminf(mred[2][0], mred[2][1]), fminf(mred[2][2], mred[2][3]));
    float m3 = fminf(fminf(mred[3][0], mred[3][1]), fminf(mred[3][2], mred[3][3]));
    float s0 = 0.f, s1 = 0.f, s2 = 0.f, s3 = 0.f;
#pragma unroll
    for (int jj = 0; jj < 4; ++jj) {
      a0[jj] = __builtin_amdgcn_exp2f((m0 - a0[jj]) * L2E2); s0 += a0[jj];
      a1[jj] = __builtin_amdgcn_exp2f((m1 - a1[jj]) * L2E2); s1 += a1[jj];
      a2[jj] = __builtin_amdgcn_exp2f((m2 - a2[jj]) * L2E2); s2 += a2[jj];
      a3[jj] = __builtin_amdgcn_exp2f((m3 - a3[jj]) * L2E2); s3 += a3[jj];
    }
#pragma unroll
    for (int off = 32; off > 0; off >>= 1) {
      s0 += __shfl_xor(s0, off); s1 += __shfl_xor(s1, off);
      s2 += __shfl_xor(s2, off); s3 += __shfl_xor(s3, off);
    }
    if (lane == 0) {
      sred[0][wave] = s0; sred[1][wave] = s1;
      sred[2][wave] = s2; sred[3][wave] = s3;
    }
    __syncthreads();
    float i0 = __builtin_amdgcn_rcpf(sred[0][0] + sred[0][1] + sred[0][2] + sred[0][3]);
    float i1 = __builtin_amdgcn_rcpf(sred[1][0] + sred[1][1] + sred[1][2] + sred[1][3]);
    float i2 = __builtin_amdgcn_rcpf(sred[2][0] + sred[2][1] + sred[2][2] + sred[2][3]);
    float i3 = __builtin_amdgcn_rcpf(sred[3][0] + sred[3][1] + sred[3][2] + sred[3][3]);
    float* __restrict__ ar0 = attn_out + (size_t)(row0 + 0) * LK;
    float* __restrict__ ar1 = attn_out + (size_t)(row0 + 1) * LK;
    float* __restrict__ ar2 = attn_out + (size_t)(row0 + 2) * LK;
    float* __restrict__ ar3 = attn_out + (size_t)(row0 + 3) * LK;
#pragma unroll
    for (int jj = 0; jj < 4; ++jj) {
      float p0 = a0[jj] * i0, p1 = a1[jj] * i1;
      float p2 = a2[jj] * i2, p3 = a3[jj] * i3;
      sc[0][tid + jj * 256] = p0; ar0[tid + jj * 256] = p0;
      sc[1][tid + jj * 256] = p1; ar1[tid + jj * 256] = p1;
      sc[2][tid + jj * 256] = p2; ar2[tid + jj * 256] = p2;
      sc[3][tid + jj * 256] = p3; ar3[tid + jj * 256] = p3;
    }
  }
  __syncthreads();

  // PV: wave owns 256-j slice; vp read once per block per j (serves 4 rows)
  {
    const int jj = lane >> 4, l16 = lane & 15;
    const float4* __restrict__ vp4 = (const float4*)vp_b;
    float4 a[RB];
#pragma unroll
    for (int r = 0; r < RB; ++r) a[r] = make_float4(0.f, 0.f, 0.f, 0.f);
#pragma unroll 4
    for (int it = 0; it < 64; ++it) {
      int j = (wave << 8) + (it << 2) + jj;
      float4 vv = vp4[(size_t)j * (DK / 4) + l16];
#pragma unroll
      for (int r = 0; r < RB; ++r) {
        float pw = sc[r][j];
        a[r].x = fmaf(pw, vv.x, a[r].x);
        a[r].y = fmaf(pw, vv.y, a[r].y);
        a[r].z = fmaf(pw, vv.z, a[r].z);
        a[r].w = fmaf(pw, vv.w, a[r].w);
      }
    }
#pragma unroll
    for (int r = 0; r < RB; ++r) {
      a[r].x += __shfl_xor(a[r].x, 16); a[r].y += __shfl_xor(a[r].y, 16);
      a[r].z += __shfl_xor(a[r].z, 16); a[r].w += __shfl_xor(a[r].w, 16);
      a[r].x += __shfl_xor(a[r].x, 32); a[r].y += __shfl_xor(a[r].y, 32);
      a[r].z += __shfl_xor(a[r].z, 32); a[r].w += __shfl_xor(a[r].w, 32);
    }
    if (jj == 0) {
#pragma unroll
      for (int r = 0; r < RB; ++r) pvred[wave][r][l16] = a[r];
    }
  }
  __syncthreads();
  if (tid < 64) {  // final PV reduce -> transposed ovlT[e][r]
    int r = tid >> 4, l16 = tid & 15;
    float4 s = make_float4(0.f, 0.f, 0.f, 0.f);
#pragma unroll
    for (int w = 0; w < 4; ++w) {
      float4 t = pvred[w][r][l16];
      s.x += t.x; s.y += t.y; s.z += t.z; s.w += t.w;
    }
    ovlT[l16 * 4 + 0][r] = s.x;
    ovlT[l16 * 4 + 1][r] = s.y;
    ovlT[l16 * 4 + 2][r] = s.z;
    ovlT[l16 * 4 + 3][r] = s.w;
  }
  __syncthreads();

  // FC + residual + LN: thread owns columns c, c+256 of 4 rows
  {
    const int c0 = tid, c1 = tid + 256;
    float y[RB][2];
#pragma unroll
    for (int r = 0; r < RB; ++r) {
      y[r][0] = resid[(size_t)(row0 + r) * D_MODEL + c0];
      y[r][1] = resid[(size_t)(row0 + r) * D_MODEL + c1];
    }
#pragma unroll 4
    for (int e = 0; e < DK; ++e) {
      float w0 = Wfc[(size_t)e * D_MODEL + c0];
      float w1 = Wfc[(size_t)e * D_MODEL + c1];
      float4 ov = *(const float4*)&ovlT[e][0];
      y[0][0] = fmaf(ov.x, w0, y[0][0]); y[0][1] = fmaf(ov.x, w1, y[0][1]);
      y[1][0] = fmaf(ov.y, w0, y[1][0]); y[1][1] = fmaf(ov.y, w1, y[1][1]);
      y[2][0] = fmaf(ov.z, w0, y[2][0]); y[2][1] = fmaf(ov.z, w1, y[2][1]);
      y[3][0] = fmaf(ov.w, w0, y[3][0]); y[3][1] = fmaf(ov.w, w1, y[3][1]);
    }
#pragma unroll
    for (int r = 0; r < RB; ++r) {
      float s = y[r][0] + y[r][1];
#pragma unroll
      for (int off = 32; off > 0; off >>= 1) s += __shfl_xor(s, off);
      if (lane == 0) red[0][r][wave] = s;
    }
    __syncthreads();
    float mu[RB];
#pragma unroll
    for (int r = 0; r < RB; ++r)
      mu[r] = (red[0][r][0] + red[0][r][1] + red[0][r][2] + red[0][r][3]) *
              (1.0f / D_MODEL);
#pragma unroll
    for (int r = 0; r < RB; ++r) {
      float d0 = y[r][0] - mu[r], d1 = y[r][1] - mu[r];
      float s = d0 * d0 + d1 * d1;
#pragma unroll
      for (int off = 32; off > 0; off >>= 1) s += __shfl_xor(s, off);
      if (lane == 0) red[1][r][wave] = s;
    }
    __syncthreads();
    float g0 = gamma[c0], g1 = gamma[c1], b0 = beta[c0], b1 = beta[c1];
#pragma unroll
    for (int r = 0; r < RB; ++r) {
      float var = (red[1][r][0] + red[1][r][1] + red[1][r][2] + red[1][r][3]) *
                  (1.0f / D_MODEL);
      float rstd = rsqrtf(var + LN_EPS);
      out[(size_t)(row0 + r) * D_MODEL + c0] = (y[r][0] - mu[r]) * rstd * g0 + b0;
      out[(size_t)(row0 + r) * D_MODEL + c1] = (y[r][1] - mu[r]) * rstd * g1 + b1;
    }
  }
}

extern "C" void kernel_launch(void* const* d_in, const int* in_sizes, int n_in,
                              void* d_out, int out_size, void* d_ws,
                              size_t ws_size, hipStream_t stream) {
  const float* q = (const float*)d_in[0];
  const float* k = (const float*)d_in[1];
  const float* v = (const float*)d_in[2];
  const float* Wq = (const float*)d_in[3];
  const float* Wk = (const float*)d_in[4];
  const float* Wv = (const float*)d_in[5];
  const float* v_param = (const float*)d_in[6];
  const float* Wfc = (const float*)d_in[7];
  const float* gamma = (const float*)d_in[8];
  const float* beta = (const float*)d_in[9];

  float* out = (float*)d_out;                     // [B*LQ*D_MODEL]
  float* attn = out + (size_t)NB * LQ * D_MODEL;  // [B*LQ*LK]

  float* base = (float*)d_ws;
  float4* ab4 = (float4*)base;                       // 2048*32 float4 (1 MB)
  float* p1 = base + (size_t)NB * LQ * 32 * 4;       // floats consumed by ab4
  float2* ekT2 = (float2*)p1;                        // 2*32*1024 float2 (512 KB)
  float* vp = p1 + (size_t)NB * 32 * LK * 2;         // [2048*64]

  hipLaunchKernelGGL(proj_kernel, dim3(3 * 128), dim3(256), 0, stream, q, k, v,
                     Wq, Wk, Wv, v_param, ab4, ekT2, vp);
  hipLaunchKernelGGL(attn_kernel, dim3(NB * LQ / RB), dim3(256), 0, stream,
                     ab4, ekT2, vp, q, Wfc, gamma, beta, out, attn);
}